// Round 1
// baseline (1342.468 us; speedup 1.0000x reference)
//
#include <hip/hip_runtime.h>
#include <stdint.h>

#define SEQ 4096
#define DIM_ 512

typedef float f32x4 __attribute__((ext_vector_type(4)));
typedef short bf16x8 __attribute__((ext_vector_type(8)));

static __device__ __forceinline__ short f2bf(float f) {
  uint32_t u = __builtin_bit_cast(uint32_t, f);
  u += 0x7fffu + ((u >> 16) & 1u);
  return (short)(u >> 16);
}
static __device__ __forceinline__ float bf2f(short s) {
  uint32_t u = ((uint32_t)(uint16_t)s) << 16;
  return __builtin_bit_cast(float, u);
}
static __device__ __forceinline__ f32x4 zero4() {
  f32x4 z; z[0] = 0.f; z[1] = 0.f; z[2] = 0.f; z[3] = 0.f; return z;
}

// ---------------- LN over text/img -> bf16 norms [4][S][D] ----------------
__global__ __launch_bounds__(256) void ln_kernel(
    const float* __restrict__ text, const float* __restrict__ img,
    const float* __restrict__ gt, const float* __restrict__ bt,
    const float* __restrict__ gi, const float* __restrict__ bi,
    short* __restrict__ norms)
{
  int row = blockIdx.x;            // 0..16383 ; batch = row>>12
  int batch = row >> 12;
  int tid = threadIdx.x;
  const float* g = (batch < 2) ? gt : gi;
  const float* b = (batch < 2) ? bt : bi;
  const float* src = (batch < 2) ? (text + (size_t)row * DIM_)
                                 : (img + (size_t)(row - 2 * SEQ) * DIM_);
  float x0 = src[tid], x1 = src[tid + 256];
  float s1 = x0 + x1, s2 = x0 * x0 + x1 * x1;
  #pragma unroll
  for (int off = 32; off; off >>= 1) { s1 += __shfl_xor(s1, off); s2 += __shfl_xor(s2, off); }
  __shared__ float rs1[4], rs2[4];
  int w = tid >> 6;
  if ((tid & 63) == 0) { rs1[w] = s1; rs2[w] = s2; }
  __syncthreads();
  float t1 = rs1[0] + rs1[1] + rs1[2] + rs1[3];
  float t2 = rs2[0] + rs2[1] + rs2[2] + rs2[3];
  float mu = t1 * (1.0f / DIM_);
  float var = t2 * (1.0f / DIM_) - mu * mu;
  float r = rsqrtf(var + 1e-5f);
  norms[(size_t)row * DIM_ + tid]       = f2bf((x0 - mu) * r * g[tid] + b[tid]);
  norms[(size_t)row * DIM_ + tid + 256] = f2bf((x1 - mu) * r * g[tid + 256] + b[tid + 256]);
}

// ---------------- pack weights: Wstack bf16 [4][1536][512], WoB bf16, bstack f32 [4][1536] ----
__global__ __launch_bounds__(256) void prep_w(
    const float* __restrict__ Wq,  const float* __restrict__ Wkt, const float* __restrict__ Wvt,
    const float* __restrict__ Wki, const float* __restrict__ Wvi, const float* __restrict__ Wo,
    const float* __restrict__ bq,  const float* __restrict__ bkt, const float* __restrict__ bvt,
    const float* __restrict__ bki, const float* __restrict__ bvi,
    short* __restrict__ Wstack, short* __restrict__ WoB, float* __restrict__ bstack)
{
  int idx = blockIdx.x * 256 + threadIdx.x;
  const int WS = 4 * 1536 * 512;   // 3,145,728
  if (idx < WS) {
    int b = idx / 786432;
    int rem = idx - b * 786432;
    int rr = rem >> 9, cc = rem & 511;
    float v;
    if (rr < 512)       v = Wq[rr * 512 + cc];
    else if (rr < 1024) v = (b < 2 ? Wkt : Wki)[(rr - 512) * 512 + cc];
    else                v = (b < 2 ? Wvt : Wvi)[(rr - 1024) * 512 + cc];
    Wstack[idx] = f2bf(v);
  } else {
    int j = idx - WS;              // 0..262143, grid sized exactly
    WoB[j] = f2bf(Wo[j]);
  }
  if (idx < 6144) {
    int b = idx / 1536, rr = idx - b * 1536;
    float v;
    if (rr < 512)       v = bq[rr];
    else if (rr < 1024) v = (b < 2 ? bkt : bki)[rr - 512];
    else                v = (b < 2 ? bvt : bvi)[rr - 1024];
    bstack[idx] = v;
  }
}

// ---------------- generic bf16 GEMM: C[m][n] = sum_k A[m][k]*W[n][k] + bias[n] ----------------
// tile 128x128, BK=64, 4 waves each 64x64 (4x4 frags of 16x16x32 bf16 MFMA)
__global__ __launch_bounds__(256) void gemm_kernel(
    const short* __restrict__ A, long long aBS,
    const short* __restrict__ W, long long wBS,
    const float* __restrict__ bias, int bBS,
    short* __restrict__ out, long long outBS, long long segStride)
{
  __shared__ short As[128 * 72], Bs[128 * 72];
  int b = blockIdx.z;
  A += (size_t)b * aBS; W += (size_t)b * wBS; bias += (size_t)b * bBS;
  int m0 = blockIdx.x * 128, n0 = blockIdx.y * 128;
  int tid = threadIdx.x;
  int w = tid >> 6, lane = tid & 63, quad = lane >> 4, l16 = lane & 15;
  int wr = (w & 1) * 64, wc = (w >> 1) * 64;
  f32x4 acc[4][4];
  #pragma unroll
  for (int i = 0; i < 4; i++)
    #pragma unroll
    for (int j = 0; j < 4; j++) acc[i][j] = zero4();

  for (int kc = 0; kc < 8; ++kc) {
    __syncthreads();
    #pragma unroll
    for (int i = 0; i < 4; ++i) {
      int flat = i * 256 + tid;
      int r = flat >> 3, c = flat & 7;
      *(uint4*)(&As[r * 72 + c * 8]) = *(const uint4*)(A + (size_t)(m0 + r) * 512 + kc * 64 + c * 8);
      *(uint4*)(&Bs[r * 72 + c * 8]) = *(const uint4*)(W + (size_t)(n0 + r) * 512 + kc * 64 + c * 8);
    }
    __syncthreads();
    #pragma unroll
    for (int ks = 0; ks < 2; ++ks) {
      bf16x8 af[4], bfv[4];
      #pragma unroll
      for (int mi = 0; mi < 4; mi++)
        af[mi] = *(const bf16x8*)(&As[(wr + mi * 16 + l16) * 72 + ks * 32 + quad * 8]);
      #pragma unroll
      for (int ni = 0; ni < 4; ni++)
        bfv[ni] = *(const bf16x8*)(&Bs[(wc + ni * 16 + l16) * 72 + ks * 32 + quad * 8]);
      #pragma unroll
      for (int mi = 0; mi < 4; mi++)
        #pragma unroll
        for (int ni = 0; ni < 4; ni++)
          acc[mi][ni] = __builtin_amdgcn_mfma_f32_16x16x32_bf16(af[mi], bfv[ni], acc[mi][ni], 0, 0, 0);
    }
  }
  #pragma unroll
  for (int mi = 0; mi < 4; mi++) {
    #pragma unroll
    for (int ni = 0; ni < 4; ni++) {
      int ng = n0 + wc + ni * 16 + l16;
      int seg = ng >> 9, col = ng & 511;
      float bv = bias[ng];
      #pragma unroll
      for (int r = 0; r < 4; r++) {
        int mg = m0 + wr + mi * 16 + quad * 4 + r;
        out[(size_t)b * outBS + (size_t)seg * segStride + (size_t)mg * 512 + col] =
            f2bf(acc[mi][ni][r] + bv);
      }
    }
  }
}

// ---------------- V [4][S][D] -> Vt [4][D][S] (bf16) ----------------
__global__ __launch_bounds__(256) void transpose_kernel(const short* __restrict__ V, short* __restrict__ Vt)
{
  __shared__ short T[64 * 72];
  int b = blockIdx.z;
  int s0 = blockIdx.x * 64, d0 = blockIdx.y * 64;
  int tid = threadIdx.x;
  const short* Vb = V + (size_t)b * SEQ * 512;
  short* Vtb = Vt + (size_t)b * 512 * SEQ;
  #pragma unroll
  for (int i = 0; i < 2; ++i) {
    int flat = i * 256 + tid;
    int r = flat >> 3, c8 = flat & 7;
    bf16x8 v = *(const bf16x8*)(Vb + (size_t)(s0 + r) * 512 + d0 + c8 * 8);
    #pragma unroll
    for (int j = 0; j < 8; ++j) T[(c8 * 8 + j) * 72 + r] = v[j];
  }
  __syncthreads();
  #pragma unroll
  for (int i = 0; i < 2; ++i) {
    int flat = i * 256 + tid;
    int dl = flat & 63, sc = flat >> 6;
    uint4 v = *(const uint4*)(&T[dl * 72 + sc * 8]);
    *(uint4*)(Vtb + (size_t)(d0 + dl) * SEQ + s0 + sc * 8) = v;
  }
}

// ---------------- flash attention: Mq=64 per block, Nk=128 per iter ----------------
// 4 waves: S-phase wave (rg=w>>1 rows 32*rg.., kg=w&1 keys 64*kg..); PV-phase wave owns d-slice w*128..
__global__ __launch_bounds__(256, 1) void attn_kernel(
    const short* __restrict__ Q, const short* __restrict__ K,
    const short* __restrict__ Vt, short* __restrict__ X)
{
  __shared__ short kv[69632];          // union: K-tile [128][520] / Vt-tile [512][136]
  __shared__ short P[64 * 136];        // probs tile [64 rows][128 keys], stride 136
  __shared__ float redm[2][64], reds[2][64], mst[64], lst[64], alph[64];

  int b = blockIdx.x >> 6, qt = blockIdx.x & 63;
  const short* Qb  = Q  + ((size_t)b * SEQ + qt * 64) * 512;
  const short* Kb  = K  + (size_t)b * SEQ * 512;
  const short* Vtb = Vt + (size_t)b * 512 * SEQ;
  short* Xb = X + ((size_t)b * SEQ + qt * 64) * 512;
  int tid = threadIdx.x;
  int w = tid >> 6, lane = tid & 63, quad = lane >> 4, l16 = lane & 15;
  int rg = w >> 1, kg = w & 1;
  const float cf = 0.044194173824159216f * 1.4426950408889634f;  // scale * log2(e)

  // q fragments in registers: rows rg*32..rg*32+32, full depth 512
  bf16x8 qf[2][16];
  #pragma unroll
  for (int mi = 0; mi < 2; mi++)
    #pragma unroll
    for (int ks = 0; ks < 16; ks++)
      qf[mi][ks] = *(const bf16x8*)(Qb + (size_t)(rg * 32 + mi * 16 + l16) * 512 + ks * 32 + quad * 8);

  if (tid < 64) { mst[tid] = -1e30f; lst[tid] = 0.f; }
  f32x4 o[4][8];
  #pragma unroll
  for (int i = 0; i < 4; i++)
    #pragma unroll
    for (int j = 0; j < 8; j++) o[i][j] = zero4();

  for (int kt = 0; kt < 32; ++kt) {
    __syncthreads();                                   // B0: kv reuse guard
    for (int i = 0; i < 32; ++i) {                     // stage K tile [128][512] -> stride 520
      int flat = i * 256 + tid;
      int r = flat >> 6, c = flat & 63;
      *(uint4*)(&kv[r * 520 + c * 8]) = *(const uint4*)(Kb + (size_t)(kt * 128 + r) * 512 + c * 8);
    }
    __syncthreads();                                   // B1: K ready

    f32x4 sacc[2][4];
    #pragma unroll
    for (int mi = 0; mi < 2; mi++)
      #pragma unroll
      for (int ni = 0; ni < 4; ni++) sacc[mi][ni] = zero4();

    #pragma unroll
    for (int ks = 0; ks < 16; ++ks) {
      bf16x8 bfv[4];
      #pragma unroll
      for (int ni = 0; ni < 4; ni++)
        bfv[ni] = *(const bf16x8*)(&kv[(kg * 64 + ni * 16 + l16) * 520 + ks * 32 + quad * 8]);
      #pragma unroll
      for (int mi = 0; mi < 2; mi++)
        #pragma unroll
        for (int ni = 0; ni < 4; ni++)
          sacc[mi][ni] = __builtin_amdgcn_mfma_f32_16x16x32_bf16(qf[mi][ks], bfv[ni], sacc[mi][ni], 0, 0, 0);
    }

    // local row max in scaled-log2 units
    float lm[2][4];
    #pragma unroll
    for (int mi = 0; mi < 2; mi++)
      #pragma unroll
      for (int r = 0; r < 4; r++) {
        float v = fmaxf(fmaxf(sacc[mi][0][r], sacc[mi][1][r]), fmaxf(sacc[mi][2][r], sacc[mi][3][r]));
        lm[mi][r] = v * cf;
      }
    #pragma unroll
    for (int off = 1; off <= 8; off <<= 1)
      #pragma unroll
      for (int mi = 0; mi < 2; mi++)
        #pragma unroll
        for (int r = 0; r < 4; r++) lm[mi][r] = fmaxf(lm[mi][r], __shfl_xor(lm[mi][r], off));
    if (l16 == 0) {
      #pragma unroll
      for (int mi = 0; mi < 2; mi++)
        #pragma unroll
        for (int r = 0; r < 4; r++)
          redm[kg][rg * 32 + mi * 16 + quad * 4 + r] = lm[mi][r];
    }
    __syncthreads();                                   // B2: redm ready
    if (tid < 64) {
      float mt = fmaxf(redm[0][tid], redm[1][tid]);
      float mo = mst[tid];
      float mn = fmaxf(mo, mt);
      alph[tid] = exp2f(mo - mn);
      mst[tid] = mn;
    }
    __syncthreads();                                   // B3: mst/alph ready

    float ls[2][4];
    #pragma unroll
    for (int mi = 0; mi < 2; mi++)
      #pragma unroll
      for (int r = 0; r < 4; r++) ls[mi][r] = 0.f;
    #pragma unroll
    for (int mi = 0; mi < 2; mi++) {
      float mrow[4];
      #pragma unroll
      for (int r = 0; r < 4; r++) mrow[r] = mst[rg * 32 + mi * 16 + quad * 4 + r];
      #pragma unroll
      for (int ni = 0; ni < 4; ni++) {
        #pragma unroll
        for (int r = 0; r < 4; r++) {
          float p = exp2f(sacc[mi][ni][r] * cf - mrow[r]);
          ls[mi][r] += p;
          P[(rg * 32 + mi * 16 + quad * 4 + r) * 136 + kg * 64 + ni * 16 + l16] = f2bf(p);
        }
      }
    }
    #pragma unroll
    for (int off = 1; off <= 8; off <<= 1)
      #pragma unroll
      for (int mi = 0; mi < 2; mi++)
        #pragma unroll
        for (int r = 0; r < 4; r++) ls[mi][r] += __shfl_xor(ls[mi][r], off);
    if (l16 == 0) {
      #pragma unroll
      for (int mi = 0; mi < 2; mi++)
        #pragma unroll
        for (int r = 0; r < 4; r++)
          reds[kg][rg * 32 + mi * 16 + quad * 4 + r] = ls[mi][r];
    }
    // rescale O by alpha (alph stable since B3)
    #pragma unroll
    for (int om = 0; om < 4; om++) {
      float av[4];
      #pragma unroll
      for (int r = 0; r < 4; r++) av[r] = alph[om * 16 + quad * 4 + r];
      #pragma unroll
      for (int od = 0; od < 8; od++)
        #pragma unroll
        for (int r = 0; r < 4; r++) o[om][od][r] *= av[r];
    }
    __syncthreads();                                   // B4: P + reds complete, kv free
    if (tid < 64) lst[tid] = alph[tid] * lst[tid] + reds[0][tid] + reds[1][tid];
    for (int i = 0; i < 32; ++i) {                     // stage Vt tile [512][128] -> stride 136
      int flat = i * 256 + tid;
      int r = flat >> 4, c = flat & 15;
      *(uint4*)(&kv[r * 136 + c * 8]) = *(const uint4*)(Vtb + (size_t)r * SEQ + kt * 128 + c * 8);
    }
    __syncthreads();                                   // B5: Vt ready

    #pragma unroll
    for (int vc = 0; vc < 4; ++vc) {
      bf16x8 pa[4];
      #pragma unroll
      for (int om = 0; om < 4; om++)
        pa[om] = *(const bf16x8*)(&P[(om * 16 + l16) * 136 + vc * 32 + quad * 8]);
      #pragma unroll
      for (int od = 0; od < 8; od++) {
        bf16x8 vb = *(const bf16x8*)(&kv[(w * 128 + od * 16 + l16) * 136 + vc * 32 + quad * 8]);
        #pragma unroll
        for (int om = 0; om < 4; om++)
          o[om][od] = __builtin_amdgcn_mfma_f32_16x16x32_bf16(pa[om], vb, o[om][od], 0, 0, 0);
      }
    }
  }

  // epilogue: X = O / l  (lst stable since last B5)
  #pragma unroll
  for (int om = 0; om < 4; om++) {
    float li[4];
    #pragma unroll
    for (int r = 0; r < 4; r++) li[r] = 1.0f / lst[om * 16 + quad * 4 + r];
    #pragma unroll
    for (int od = 0; od < 8; od++)
      #pragma unroll
      for (int r = 0; r < 4; r++)
        Xb[(size_t)(om * 16 + quad * 4 + r) * 512 + w * 128 + od * 16 + l16] =
            f2bf(o[om][od][r] * li[r]);
  }
}

// ---------------- final dual LN: X2 bf16 [4][S][D] -> out f32 [8][S][D] ----------------
__global__ __launch_bounds__(256) void fln_kernel(
    const short* __restrict__ X2,
    const float* __restrict__ gt, const float* __restrict__ bt,
    const float* __restrict__ gi, const float* __restrict__ bi,
    float* __restrict__ out)
{
  int row = blockIdx.x;   // 0..16383
  int tid = threadIdx.x;
  const short* src = X2 + (size_t)row * 512;
  float x0 = bf2f(src[tid]), x1 = bf2f(src[tid + 256]);
  float s1 = x0 + x1, s2 = x0 * x0 + x1 * x1;
  #pragma unroll
  for (int off = 32; off; off >>= 1) { s1 += __shfl_xor(s1, off); s2 += __shfl_xor(s2, off); }
  __shared__ float rs1[4], rs2[4];
  int w = tid >> 6;
  if ((tid & 63) == 0) { rs1[w] = s1; rs2[w] = s2; }
  __syncthreads();
  float t1 = rs1[0] + rs1[1] + rs1[2] + rs1[3];
  float t2 = rs2[0] + rs2[1] + rs2[2] + rs2[3];
  float mu = t1 * (1.0f / DIM_);
  float var = t2 * (1.0f / DIM_) - mu * mu;
  float r = rsqrtf(var + 1e-5f);
  float n0 = (x0 - mu) * r, n1 = (x1 - mu) * r;
  out[(size_t)row * 512 + tid]                   = n0 * gt[tid] + bt[tid];
  out[(size_t)row * 512 + tid + 256]             = n1 * gt[tid + 256] + bt[tid + 256];
  out[(size_t)(row + 16384) * 512 + tid]         = n0 * gi[tid] + bi[tid];
  out[(size_t)(row + 16384) * 512 + tid + 256]   = n1 * gi[tid + 256] + bi[tid + 256];
}

extern "C" void kernel_launch(void* const* d_in, const int* in_sizes, int n_in,
                              void* d_out, int out_size, void* d_ws, size_t ws_size,
                              hipStream_t stream) {
  const float* text  = (const float*)d_in[0];
  const float* img   = (const float*)d_in[1];
  const float* ln_t_g = (const float*)d_in[2];
  const float* ln_t_b = (const float*)d_in[3];
  const float* ln_i_g = (const float*)d_in[4];
  const float* ln_i_b = (const float*)d_in[5];
  const float* Wq  = (const float*)d_in[6];  const float* bq  = (const float*)d_in[7];
  const float* Wkt = (const float*)d_in[8];  const float* bkt = (const float*)d_in[9];
  const float* Wvt = (const float*)d_in[10]; const float* bvt = (const float*)d_in[11];
  const float* Wki = (const float*)d_in[12]; const float* bki = (const float*)d_in[13];
  const float* Wvi = (const float*)d_in[14]; const float* bvi = (const float*)d_in[15];
  const float* Wo  = (const float*)d_in[16]; const float* bo  = (const float*)d_in[17];

  const size_t NE = (size_t)4 * SEQ * DIM_;   // 8,388,608 elems per [4][S][D]
  short* norms  = (short*)d_ws;
  short* Qp     = norms + NE;
  short* Kp     = Qp + NE;
  short* Vp     = Kp + NE;
  short* Vtp    = Vp + NE;
  short* Xp     = Vtp + NE;
  short* X2p    = Xp + NE;
  short* Wstack = X2p + NE;
  short* WoB    = Wstack + (size_t)4 * 1536 * 512;
  float* bstack = (float*)(WoB + (size_t)512 * 512);

  ln_kernel<<<dim3(16384), dim3(256), 0, stream>>>(text, img, ln_t_g, ln_t_b, ln_i_g, ln_i_b, norms);
  prep_w<<<dim3(13312), dim3(256), 0, stream>>>(Wq, Wkt, Wvt, Wki, Wvi, Wo,
                                                bq, bkt, bvt, bki, bvi, Wstack, WoB, bstack);
  // Q|K|V projection: per batch, A=norms[b] (4096x512), W=Wstack[b] (1536x512)
  gemm_kernel<<<dim3(32, 12, 4), dim3(256), 0, stream>>>(
      norms, (long long)(SEQ * DIM_), Wstack, (long long)(1536 * 512), bstack, 1536,
      Qp, (long long)(SEQ * DIM_), (long long)NE);
  transpose_kernel<<<dim3(64, 8, 4), dim3(256), 0, stream>>>(Vp, Vtp);
  attn_kernel<<<dim3(256), dim3(256), 0, stream>>>(Qp, Kp, Vtp, Xp);
  // output projection: A=X (16384x512), W=WoB (512x512)
  gemm_kernel<<<dim3(128, 4, 1), dim3(256), 0, stream>>>(
      Xp, 0LL, WoB, 0LL, bo, 0,
      X2p, 0LL, 0LL);
  fln_kernel<<<dim3(16384), dim3(256), 0, stream>>>(X2p, ln_t_g, ln_t_b, ln_i_g, ln_i_b, (float*)d_out);
}

// Round 2
// 667.240 us; speedup vs baseline: 2.0120x; 2.0120x over previous
//
#include <hip/hip_runtime.h>
#include <stdint.h>

#define SEQ 4096
#define DIM_ 512

typedef float f32x4 __attribute__((ext_vector_type(4)));
typedef short bf16x8 __attribute__((ext_vector_type(8)));

static __device__ __forceinline__ short f2bf(float f) {
  uint32_t u = __builtin_bit_cast(uint32_t, f);
  u += 0x7fffu + ((u >> 16) & 1u);
  return (short)(u >> 16);
}
static __device__ __forceinline__ float bf2f(short s) {
  uint32_t u = ((uint32_t)(uint16_t)s) << 16;
  return __builtin_bit_cast(float, u);
}
static __device__ __forceinline__ f32x4 zero4() {
  f32x4 z; z[0] = 0.f; z[1] = 0.f; z[2] = 0.f; z[3] = 0.f; return z;
}

// async global->LDS, 16B per lane, lands at ldsbase + lane*16
static __device__ __forceinline__ void async_load16(const short* g, short* l) {
  __builtin_amdgcn_global_load_lds(
      (const __attribute__((address_space(1))) void*)g,
      (__attribute__((address_space(3))) void*)l,
      16, 0, 0);
}

// ---------------- LN over text/img -> bf16 norms [4][S][D] ----------------
__global__ __launch_bounds__(256) void ln_kernel(
    const float* __restrict__ text, const float* __restrict__ img,
    const float* __restrict__ gt, const float* __restrict__ bt,
    const float* __restrict__ gi, const float* __restrict__ bi,
    short* __restrict__ norms)
{
  int row = blockIdx.x;            // 0..16383 ; batch = row>>12
  int batch = row >> 12;
  int tid = threadIdx.x;
  const float* g = (batch < 2) ? gt : gi;
  const float* b = (batch < 2) ? bt : bi;
  const float* src = (batch < 2) ? (text + (size_t)row * DIM_)
                                 : (img + (size_t)(row - 2 * SEQ) * DIM_);
  float x0 = src[tid], x1 = src[tid + 256];
  float s1 = x0 + x1, s2 = x0 * x0 + x1 * x1;
  #pragma unroll
  for (int off = 32; off; off >>= 1) { s1 += __shfl_xor(s1, off); s2 += __shfl_xor(s2, off); }
  __shared__ float rs1[4], rs2[4];
  int w = tid >> 6;
  if ((tid & 63) == 0) { rs1[w] = s1; rs2[w] = s2; }
  __syncthreads();
  float t1 = rs1[0] + rs1[1] + rs1[2] + rs1[3];
  float t2 = rs2[0] + rs2[1] + rs2[2] + rs2[3];
  float mu = t1 * (1.0f / DIM_);
  float var = t2 * (1.0f / DIM_) - mu * mu;
  float r = rsqrtf(var + 1e-5f);
  norms[(size_t)row * DIM_ + tid]       = f2bf((x0 - mu) * r * g[tid] + b[tid]);
  norms[(size_t)row * DIM_ + tid + 256] = f2bf((x1 - mu) * r * g[tid + 256] + b[tid + 256]);
}

// ---------------- pack weights: Wstack bf16 [4][1536][512], WoB bf16, bstack f32 [4][1536] ----
__global__ __launch_bounds__(256) void prep_w(
    const float* __restrict__ Wq,  const float* __restrict__ Wkt, const float* __restrict__ Wvt,
    const float* __restrict__ Wki, const float* __restrict__ Wvi, const float* __restrict__ Wo,
    const float* __restrict__ bq,  const float* __restrict__ bkt, const float* __restrict__ bvt,
    const float* __restrict__ bki, const float* __restrict__ bvi,
    short* __restrict__ Wstack, short* __restrict__ WoB, float* __restrict__ bstack)
{
  int idx = blockIdx.x * 256 + threadIdx.x;
  const int WS = 4 * 1536 * 512;   // 3,145,728
  if (idx < WS) {
    int b = idx / 786432;
    int rem = idx - b * 786432;
    int rr = rem >> 9, cc = rem & 511;
    float v;
    if (rr < 512)       v = Wq[rr * 512 + cc];
    else if (rr < 1024) v = (b < 2 ? Wkt : Wki)[(rr - 512) * 512 + cc];
    else                v = (b < 2 ? Wvt : Wvi)[(rr - 1024) * 512 + cc];
    Wstack[idx] = f2bf(v);
  } else {
    int j = idx - WS;              // 0..262143, grid sized exactly
    WoB[j] = f2bf(Wo[j]);
  }
  if (idx < 6144) {
    int b = idx / 1536, rr = idx - b * 1536;
    float v;
    if (rr < 512)       v = bq[rr];
    else if (rr < 1024) v = (b < 2 ? bkt : bki)[rr - 512];
    else                v = (b < 2 ? bvt : bvi)[rr - 1024];
    bstack[idx] = v;
  }
}

// ---------------- generic bf16 GEMM: C[m][n] = sum_k A[m][k]*W[n][k] + bias[n] ----------------
// tile 128x128, BK=64, 4 waves each 64x64 (4x4 frags of 16x16x32 bf16 MFMA)
__global__ __launch_bounds__(256) void gemm_kernel(
    const short* __restrict__ A, long long aBS,
    const short* __restrict__ W, long long wBS,
    const float* __restrict__ bias, int bBS,
    short* __restrict__ out, long long outBS, long long segStride)
{
  __shared__ short As[128 * 72], Bs[128 * 72];
  int b = blockIdx.z;
  A += (size_t)b * aBS; W += (size_t)b * wBS; bias += (size_t)b * bBS;
  int m0 = blockIdx.x * 128, n0 = blockIdx.y * 128;
  int tid = threadIdx.x;
  int w = tid >> 6, lane = tid & 63, quad = lane >> 4, l16 = lane & 15;
  int wr = (w & 1) * 64, wc = (w >> 1) * 64;
  f32x4 acc[4][4];
  #pragma unroll
  for (int i = 0; i < 4; i++)
    #pragma unroll
    for (int j = 0; j < 4; j++) acc[i][j] = zero4();

  for (int kc = 0; kc < 8; ++kc) {
    __syncthreads();
    #pragma unroll
    for (int i = 0; i < 4; ++i) {
      int flat = i * 256 + tid;
      int r = flat >> 3, c = flat & 7;
      *(uint4*)(&As[r * 72 + c * 8]) = *(const uint4*)(A + (size_t)(m0 + r) * 512 + kc * 64 + c * 8);
      *(uint4*)(&Bs[r * 72 + c * 8]) = *(const uint4*)(W + (size_t)(n0 + r) * 512 + kc * 64 + c * 8);
    }
    __syncthreads();
    #pragma unroll
    for (int ks = 0; ks < 2; ++ks) {
      bf16x8 af[4], bfv[4];
      #pragma unroll
      for (int mi = 0; mi < 4; mi++)
        af[mi] = *(const bf16x8*)(&As[(wr + mi * 16 + l16) * 72 + ks * 32 + quad * 8]);
      #pragma unroll
      for (int ni = 0; ni < 4; ni++)
        bfv[ni] = *(const bf16x8*)(&Bs[(wc + ni * 16 + l16) * 72 + ks * 32 + quad * 8]);
      #pragma unroll
      for (int mi = 0; mi < 4; mi++)
        #pragma unroll
        for (int ni = 0; ni < 4; ni++)
          acc[mi][ni] = __builtin_amdgcn_mfma_f32_16x16x32_bf16(af[mi], bfv[ni], acc[mi][ni], 0, 0, 0);
    }
  }
  #pragma unroll
  for (int mi = 0; mi < 4; mi++) {
    #pragma unroll
    for (int ni = 0; ni < 4; ni++) {
      int ng = n0 + wc + ni * 16 + l16;
      int seg = ng >> 9, col = ng & 511;
      float bv = bias[ng];
      #pragma unroll
      for (int r = 0; r < 4; r++) {
        int mg = m0 + wr + mi * 16 + quad * 4 + r;
        out[(size_t)b * outBS + (size_t)seg * segStride + (size_t)mg * 512 + col] =
            f2bf(acc[mi][ni][r] + bv);
      }
    }
  }
}

// ---------------- V [4][S][D] -> Vt [4][D][S] (bf16) ----------------
__global__ __launch_bounds__(256) void transpose_kernel(const short* __restrict__ V, short* __restrict__ Vt)
{
  __shared__ short T[64 * 72];
  int b = blockIdx.z;
  int s0 = blockIdx.x * 64, d0 = blockIdx.y * 64;
  int tid = threadIdx.x;
  const short* Vb = V + (size_t)b * SEQ * 512;
  short* Vtb = Vt + (size_t)b * 512 * SEQ;
  #pragma unroll
  for (int i = 0; i < 2; ++i) {
    int flat = i * 256 + tid;
    int r = flat >> 3, c8 = flat & 7;
    bf16x8 v = *(const bf16x8*)(Vb + (size_t)(s0 + r) * 512 + d0 + c8 * 8);
    #pragma unroll
    for (int j = 0; j < 8; ++j) T[(c8 * 8 + j) * 72 + r] = v[j];
  }
  __syncthreads();
  #pragma unroll
  for (int i = 0; i < 2; ++i) {
    int flat = i * 256 + tid;
    int dl = flat & 63, sc = flat >> 6;
    uint4 v = *(const uint4*)(&T[dl * 72 + sc * 8]);
    *(uint4*)(Vtb + (size_t)(d0 + dl) * SEQ + s0 + sc * 8) = v;
  }
}

// ---------------- flash attention: Mq=64 per block, Nk=64 per iter, async-pipelined ----------
// LDS: Ks [64 rows][512] (XOR-swizzled 16B chunks: phys = c ^ (row&15))
//      Vs [512 rows(d)][64 keys] (XOR-swizzled: phys = c ^ (row&7))
// Waves: QK phase: rg=w>>1 rows 32*rg.., kg=w&1 keys 32*kg..; PV phase: wave owns d-slice w*128..
// Pipeline: B0 -> issue V(kt) -> QK -> B1 -> m/alpha -> B2 -> issue K(kt+1) -> P phase -> B3 -> PV
// (__syncthreads drains vmcnt(0), so each issue is hidden behind the following compute phase)
__global__ __launch_bounds__(256, 1) void attn_kernel(
    const short* __restrict__ Q, const short* __restrict__ K,
    const short* __restrict__ Vt, short* __restrict__ X)
{
  __shared__ short Ks[64 * 512];       // 64 KB
  __shared__ short Vs[512 * 64];       // 64 KB
  __shared__ short P[64 * 72];         // 9 KB, padded stride (normal ds writes)
  __shared__ float redm[2][64], reds[2][64], mst[64], lst[64], alph[64];

  int b = blockIdx.x >> 6, qt = blockIdx.x & 63;
  const short* Qb  = Q  + ((size_t)b * SEQ + qt * 64) * 512;
  const short* Kb  = K  + (size_t)b * SEQ * 512;
  const short* Vtb = Vt + (size_t)b * 512 * SEQ;
  short* Xb = X + ((size_t)b * SEQ + qt * 64) * 512;
  int tid = threadIdx.x;
  int w = tid >> 6, lane = tid & 63, quad = lane >> 4, l16 = lane & 15;
  int rg = w >> 1, kg = w & 1;
  const float cf = 0.044194173824159216f * 1.4426950408889634f;  // scale * log2(e)

  // q fragments in registers: rows rg*32..rg*32+32, full depth 512 (128 VGPRs)
  bf16x8 qf[2][16];
  #pragma unroll
  for (int mi = 0; mi < 2; mi++)
    #pragma unroll
    for (int ks = 0; ks < 16; ks++)
      qf[mi][ks] = *(const bf16x8*)(Qb + (size_t)(rg * 32 + mi * 16 + l16) * 512 + ks * 32 + quad * 8);

  if (tid < 64) { mst[tid] = -1e30f; lst[tid] = 0.f; }
  f32x4 o[4][8];
  #pragma unroll
  for (int i = 0; i < 4; i++)
    #pragma unroll
    for (int j = 0; j < 8; j++) o[i][j] = zero4();

  // issue K(0): wave w stages rows w*16..w*16+16, one wave-load (1024B) per row
  #pragma unroll
  for (int j = 0; j < 16; ++j) {
    int r = w * 16 + j;
    async_load16(Kb + (size_t)r * 512 + ((lane ^ (r & 15)) << 3), &Ks[r * 512]);
  }

  for (int kt = 0; kt < 64; ++kt) {
    __syncthreads();                                   // B0: K(kt) landed+visible; Vs free
    // issue V(kt): wave w stages row-groups w*16..w*16+16 (8 d-rows per wave-load)
    #pragma unroll
    for (int j = 0; j < 16; ++j) {
      int g = w * 16 + j;
      int row = g * 8 + (lane >> 3);
      int lc = (lane & 7) ^ (row & 7);
      async_load16(Vtb + (size_t)row * SEQ + kt * 64 + (lc << 3), &Vs[g * 8 * 64]);
    }

    // ---- QK: S[rg rows][kg keys] over full depth 512 ----
    f32x4 sacc[2][2];
    #pragma unroll
    for (int mi = 0; mi < 2; mi++)
      #pragma unroll
      for (int ni = 0; ni < 2; ni++) sacc[mi][ni] = zero4();
    #pragma unroll
    for (int ks = 0; ks < 16; ++ks) {
      bf16x8 bfv[2];
      #pragma unroll
      for (int ni = 0; ni < 2; ni++) {
        int row = kg * 32 + ni * 16 + l16;
        bfv[ni] = *(const bf16x8*)(&Ks[row * 512 + (((ks * 4 + quad) ^ l16) << 3)]);
      }
      #pragma unroll
      for (int mi = 0; mi < 2; mi++)
        #pragma unroll
        for (int ni = 0; ni < 2; ni++)
          sacc[mi][ni] = __builtin_amdgcn_mfma_f32_16x16x32_bf16(qf[mi][ks], bfv[ni], sacc[mi][ni], 0, 0, 0);
    }

    // local row max (scaled log2 units) + cross-l16 reduce
    float lm[2][4];
    #pragma unroll
    for (int mi = 0; mi < 2; mi++)
      #pragma unroll
      for (int r = 0; r < 4; r++)
        lm[mi][r] = fmaxf(sacc[mi][0][r], sacc[mi][1][r]) * cf;
    #pragma unroll
    for (int off = 1; off <= 8; off <<= 1)
      #pragma unroll
      for (int mi = 0; mi < 2; mi++)
        #pragma unroll
        for (int r = 0; r < 4; r++) lm[mi][r] = fmaxf(lm[mi][r], __shfl_xor(lm[mi][r], off));
    if (l16 == 0) {
      #pragma unroll
      for (int mi = 0; mi < 2; mi++)
        #pragma unroll
        for (int r = 0; r < 4; r++)
          redm[kg][rg * 32 + mi * 16 + quad * 4 + r] = lm[mi][r];
    }
    __syncthreads();                                   // B1: redm ready; Ks free; V(kt) landed
    if (tid < 64) {
      float mt = fmaxf(redm[0][tid], redm[1][tid]);
      float mo = mst[tid];
      float mn = fmaxf(mo, mt);
      alph[tid] = exp2f(mo - mn);
      mst[tid] = mn;
    }
    __syncthreads();                                   // B2: mst/alph ready
    if (kt < 63) {                                     // issue K(kt+1) (Ks free since B1)
      #pragma unroll
      for (int j = 0; j < 16; ++j) {
        int r = w * 16 + j;
        async_load16(Kb + ((size_t)(kt + 1) * 64 + r) * 512 + ((lane ^ (r & 15)) << 3), &Ks[r * 512]);
      }
    }

    // ---- P = exp2(S*cf - m), row-sums, O rescale ----
    float ls[2][4];
    #pragma unroll
    for (int mi = 0; mi < 2; mi++)
      #pragma unroll
      for (int r = 0; r < 4; r++) ls[mi][r] = 0.f;
    #pragma unroll
    for (int mi = 0; mi < 2; mi++) {
      float mrow[4];
      #pragma unroll
      for (int r = 0; r < 4; r++) mrow[r] = mst[rg * 32 + mi * 16 + quad * 4 + r];
      #pragma unroll
      for (int ni = 0; ni < 2; ni++) {
        #pragma unroll
        for (int r = 0; r < 4; r++) {
          float p = exp2f(sacc[mi][ni][r] * cf - mrow[r]);
          ls[mi][r] += p;
          P[(rg * 32 + mi * 16 + quad * 4 + r) * 72 + kg * 32 + ni * 16 + l16] = f2bf(p);
        }
      }
    }
    #pragma unroll
    for (int off = 1; off <= 8; off <<= 1)
      #pragma unroll
      for (int mi = 0; mi < 2; mi++)
        #pragma unroll
        for (int r = 0; r < 4; r++) ls[mi][r] += __shfl_xor(ls[mi][r], off);
    if (l16 == 0) {
      #pragma unroll
      for (int mi = 0; mi < 2; mi++)
        #pragma unroll
        for (int r = 0; r < 4; r++)
          reds[kg][rg * 32 + mi * 16 + quad * 4 + r] = ls[mi][r];
    }
    // rescale O by alpha (alph stable since B2)
    #pragma unroll
    for (int om = 0; om < 4; om++) {
      float av[4];
      #pragma unroll
      for (int r = 0; r < 4; r++) av[r] = alph[om * 16 + quad * 4 + r];
      #pragma unroll
      for (int od = 0; od < 8; od++)
        #pragma unroll
        for (int r = 0; r < 4; r++) o[om][od][r] *= av[r];
    }
    __syncthreads();                                   // B3: P/reds ready; K(kt+1) landed
    if (tid < 64) lst[tid] = alph[tid] * lst[tid] + reds[0][tid] + reds[1][tid];

    // ---- PV: O[64 rows][d-slice w*128..] += P * V ----
    #pragma unroll
    for (int vc = 0; vc < 2; ++vc) {
      bf16x8 pa[4];
      #pragma unroll
      for (int om = 0; om < 4; om++)
        pa[om] = *(const bf16x8*)(&P[(om * 16 + l16) * 72 + vc * 32 + quad * 8]);
      #pragma unroll
      for (int od = 0; od < 8; od++) {
        int row = w * 128 + od * 16 + l16;
        bf16x8 vb = *(const bf16x8*)(&Vs[row * 64 + ((((vc * 4 + quad) ^ (l16 & 7))) << 3)]);
        #pragma unroll
        for (int om = 0; om < 4; om++)
          o[om][od] = __builtin_amdgcn_mfma_f32_16x16x32_bf16(pa[om], vb, o[om][od], 0, 0, 0);
      }
    }
  }
  __syncthreads();                                     // lst stable for epilogue

  // epilogue: X = O / l
  #pragma unroll
  for (int om = 0; om < 4; om++) {
    float li[4];
    #pragma unroll
    for (int r = 0; r < 4; r++) li[r] = 1.0f / lst[om * 16 + quad * 4 + r];
    #pragma unroll
    for (int od = 0; od < 8; od++)
      #pragma unroll
      for (int r = 0; r < 4; r++)
        Xb[(size_t)(om * 16 + quad * 4 + r) * 512 + w * 128 + od * 16 + l16] =
            f2bf(o[om][od][r] * li[r]);
  }
}

// ---------------- final dual LN: X2 bf16 [4][S][D] -> out f32 [8][S][D] ----------------
__global__ __launch_bounds__(256) void fln_kernel(
    const short* __restrict__ X2,
    const float* __restrict__ gt, const float* __restrict__ bt,
    const float* __restrict__ gi, const float* __restrict__ bi,
    float* __restrict__ out)
{
  int row = blockIdx.x;   // 0..16383
  int tid = threadIdx.x;
  const short* src = X2 + (size_t)row * 512;
  float x0 = bf2f(src[tid]), x1 = bf2f(src[tid + 256]);
  float s1 = x0 + x1, s2 = x0 * x0 + x1 * x1;
  #pragma unroll
  for (int off = 32; off; off >>= 1) { s1 += __shfl_xor(s1, off); s2 += __shfl_xor(s2, off); }
  __shared__ float rs1[4], rs2[4];
  int w = tid >> 6;
  if ((tid & 63) == 0) { rs1[w] = s1; rs2[w] = s2; }
  __syncthreads();
  float t1 = rs1[0] + rs1[1] + rs1[2] + rs1[3];
  float t2 = rs2[0] + rs2[1] + rs2[2] + rs2[3];
  float mu = t1 * (1.0f / DIM_);
  float var = t2 * (1.0f / DIM_) - mu * mu;
  float r = rsqrtf(var + 1e-5f);
  float n0 = (x0 - mu) * r, n1 = (x1 - mu) * r;
  out[(size_t)row * 512 + tid]                   = n0 * gt[tid] + bt[tid];
  out[(size_t)row * 512 + tid + 256]             = n1 * gt[tid + 256] + bt[tid + 256];
  out[(size_t)(row + 16384) * 512 + tid]         = n0 * gi[tid] + bi[tid];
  out[(size_t)(row + 16384) * 512 + tid + 256]   = n1 * gi[tid + 256] + bi[tid + 256];
}

extern "C" void kernel_launch(void* const* d_in, const int* in_sizes, int n_in,
                              void* d_out, int out_size, void* d_ws, size_t ws_size,
                              hipStream_t stream) {
  const float* text  = (const float*)d_in[0];
  const float* img   = (const float*)d_in[1];
  const float* ln_t_g = (const float*)d_in[2];
  const float* ln_t_b = (const float*)d_in[3];
  const float* ln_i_g = (const float*)d_in[4];
  const float* ln_i_b = (const float*)d_in[5];
  const float* Wq  = (const float*)d_in[6];  const float* bq  = (const float*)d_in[7];
  const float* Wkt = (const float*)d_in[8];  const float* bkt = (const float*)d_in[9];
  const float* Wvt = (const float*)d_in[10]; const float* bvt = (const float*)d_in[11];
  const float* Wki = (const float*)d_in[12]; const float* bki = (const float*)d_in[13];
  const float* Wvi = (const float*)d_in[14]; const float* bvi = (const float*)d_in[15];
  const float* Wo  = (const float*)d_in[16]; const float* bo  = (const float*)d_in[17];

  const size_t NE = (size_t)4 * SEQ * DIM_;   // 8,388,608 elems per [4][S][D]
  short* norms  = (short*)d_ws;
  short* Qp     = norms + NE;
  short* Kp     = Qp + NE;
  short* Vp     = Kp + NE;
  short* Vtp    = Vp + NE;
  short* Xp     = Vtp + NE;
  short* X2p    = Xp + NE;
  short* Wstack = X2p + NE;
  short* WoB    = Wstack + (size_t)4 * 1536 * 512;
  float* bstack = (float*)(WoB + (size_t)512 * 512);

  ln_kernel<<<dim3(16384), dim3(256), 0, stream>>>(text, img, ln_t_g, ln_t_b, ln_i_g, ln_i_b, norms);
  prep_w<<<dim3(13312), dim3(256), 0, stream>>>(Wq, Wkt, Wvt, Wki, Wvi, Wo,
                                                bq, bkt, bvt, bki, bvi, Wstack, WoB, bstack);
  // Q|K|V projection: per batch, A=norms[b] (4096x512), W=Wstack[b] (1536x512)
  gemm_kernel<<<dim3(32, 12, 4), dim3(256), 0, stream>>>(
      norms, (long long)(SEQ * DIM_), Wstack, (long long)(1536 * 512), bstack, 1536,
      Qp, (long long)(SEQ * DIM_), (long long)NE);
  transpose_kernel<<<dim3(64, 8, 4), dim3(256), 0, stream>>>(Vp, Vtp);
  attn_kernel<<<dim3(256), dim3(256), 0, stream>>>(Qp, Kp, Vtp, Xp);
  // output projection: A=X (16384x512), W=WoB (512x512)
  gemm_kernel<<<dim3(128, 4, 1), dim3(256), 0, stream>>>(
      Xp, 0LL, WoB, 0LL, bo, 0,
      X2p, 0LL, 0LL);
  fln_kernel<<<dim3(16384), dim3(256), 0, stream>>>(X2p, ln_t_g, ln_t_b, ln_i_g, ln_i_b, (float*)d_out);
}